// Round 8
// baseline (403.943 us; speedup 1.0000x reference)
//
#include <hip/hip_runtime.h>

typedef __attribute__((ext_vector_type(4))) float f32x4;
typedef __attribute__((ext_vector_type(8))) short bf16x8;

#define MFMA16(a, b, c) __builtin_amdgcn_mfma_f32_16x16x32_bf16((a), (b), (c), 0, 0, 0)
#define LOG2E 1.44269504088896340736f

static __device__ __forceinline__ float bf2f(short u) {
  unsigned x = ((unsigned)(unsigned short)u) << 16;
  return __builtin_bit_cast(float, x);
}
static __device__ __forceinline__ short f2bf(float f) {
  unsigned u = __builtin_bit_cast(unsigned, f);
  u += 0x7fffu + ((u >> 16) & 1u);
  return (short)(u >> 16);
}
// global -> LDS direct DMA, 16B per lane (guide §5); source pre-swizzled.
static __device__ __forceinline__ void gll16(const void* g, void* l) {
  __builtin_amdgcn_global_load_lds(
      (const __attribute__((address_space(1))) unsigned*)(unsigned long long)g,
      (__attribute__((address_space(3))) unsigned*)(unsigned)(unsigned long long)l,
      16, 0, 0);
}
// HW f32 atomic add (no CAS loop): ISA §7 global_atomic_add_f32 addr-pair, data.
static __device__ __forceinline__ void atomadd_f32(float* p, float v) {
  asm volatile("global_atomic_add_f32 %0, %1, off"
               :: "v"((unsigned long long)p), "v"(v) : "memory");
}

// ---------------- f32 -> bf16 conversion (vectorized, G13) ----------------
__global__ void __launch_bounds__(256) cvt_kernel(const float* __restrict__ src,
                                                  short* __restrict__ dst,
                                                  long long n) {
  long long i = ((long long)blockIdx.x * 256 + threadIdx.x) * 8;
  const long long stride = (long long)gridDim.x * 256 * 8;
  for (; i < n; i += stride) {
    f32x4 a = *(const f32x4*)(src + i);
    f32x4 b = *(const f32x4*)(src + i + 4);
    bf16x8 o;
    o[0] = f2bf(a[0]); o[1] = f2bf(a[1]); o[2] = f2bf(a[2]); o[3] = f2bf(a[3]);
    o[4] = f2bf(b[0]); o[5] = f2bf(b[1]); o[6] = f2bf(b[2]); o[7] = f2bf(b[3]);
    *(bf16x8*)(dst + i) = o;
  }
}

// ---------------- RoPE cos/sin table: [2048][64] ----------------
__global__ void rope_table(const int* __restrict__ pos, float* __restrict__ ctab,
                           float* __restrict__ stab) {
  const int s = blockIdx.x;
  const int i = threadIdx.x;  // 0..63
  const float p = (float)pos[s];
  const float ang = p * exp2f(-(float)i * 0.3114307588956902f);
  ctab[s * 64 + i] = cosf(ang);
  stab[s * 64 + i] = sinf(ang);
}

// RoPE from f32 accumulator + bias -> bf16 qkvp (q,k regions only).
// Q heads (h<28) pre-scaled by SCALE*LOG2E (exp2-domain scores).
__global__ void __launch_bounds__(256) rope_apply2(const float* __restrict__ qkv32,
                                                   const float* __restrict__ bq,
                                                   const float* __restrict__ bk,
                                                   const float* __restrict__ ctab,
                                                   const float* __restrict__ stab,
                                                   short* __restrict__ qkvp) {
  const int idx = blockIdx.x * 256 + threadIdx.x;  // 2048*32*8
  const int c = idx & 7;
  const int h = (idx >> 3) & 31;
  const int s = idx >> 8;
  const float qs = (h < 28) ? (0.08838834764831845f * LOG2E) : 1.0f;
  const float* src = qkv32 + (size_t)s * 4608 + h * 128 + c * 8;
  const int bo = h * 128 + c * 8;
  const float* bl = (h < 28) ? (bq + bo) : (bk + bo - 3584);
  const float* cp = ctab + s * 64 + c * 8;
  const float* sp = stab + s * 64 + c * 8;
  bf16x8 lo2, hi2;
#pragma unroll
  for (int j = 0; j < 8; ++j) {
    const float x = src[j] + bl[j];
    const float y = src[j + 64] + bl[j + 64];
    const float cv = cp[j], sv = sp[j];
    lo2[j] = f2bf((x * cv - y * sv) * qs);
    hi2[j] = f2bf((y * cv + x * sv) * qs);
  }
  short* dst = qkvp + (size_t)s * 4608 + h * 128 + c * 8;
  *(bf16x8*)dst = lo2;
  *(bf16x8*)(dst + 64) = hi2;
}

// V region of f32 accumulator + bias -> V^T bf16 [4][128][2048]
__global__ void __launch_bounds__(256) v_transpose2(const float* __restrict__ qkv32,
                                                    const float* __restrict__ bv,
                                                    short* __restrict__ vtb) {
  __shared__ short t[64 * 48];
  const int dt = blockIdx.x, st = blockIdx.y, kv = blockIdx.z;
  const int tid = threadIdx.x;
  {
    const int r = tid >> 2, c8 = tid & 3;
    const float* src = qkv32 + (size_t)(st * 64 + r) * 4608 + 4096 +
                       kv * 128 + dt * 32 + c8 * 8;
    const float* bp = bv + kv * 128 + dt * 32 + c8 * 8;
#pragma unroll
    for (int j = 0; j < 8; ++j) t[r * 48 + c8 * 8 + j] = f2bf(src[j] + bp[j]);
  }
  __syncthreads();
  {
    const int d = tid >> 3, c = tid & 7;
    bf16x8 v;
#pragma unroll
    for (int i = 0; i < 8; ++i) v[i] = t[(c * 8 + i) * 48 + d];
    *(bf16x8*)(vtb + ((size_t)kv * 128 + dt * 32 + d) * 2048 + st * 64 + c * 8) = v;
  }
}

// ----- stream-K 8-phase bf16 GEMM (r7 schedule, k-unit iteration space) -----
// C(f32, zero-init) += A[M,K]*B[N,K]^T via global_atomic_add_f32 epilogues.
// 256x256 tiles, BK=64, 8 waves (2M x 4N). k-units = (tile, ktile) pairs,
// tile = unit/56 (row-major over N). MODE 0: block b owns [b*UNITS,(b+1)*UNITS)
// (spans <=2 tiles; mid-block epilogue + acc reset at boundary). MODE 1:
// aligned split-2: b -> tile b/2, half b&1 (single segment).
// Phase/sync/vmcnt schedule identical to r7 (ledger-verified); staging maps
// global unit -> (tile,kk) via boundary compare. Epilogue atomics inflate
// vmcnt -> later counted waits only get STRONGER (one bounded stall/boundary).
template <int NT, int UNITS, int MODE>
__global__ void __launch_bounds__(512, 2)
gemm_sk(const short* __restrict__ A, const short* __restrict__ B,
        float* __restrict__ Co, int N, int K) {
  __shared__ short As[2][256 * 64];
  __shared__ short Bs[2][256 * 64];
  const int bid = (int)blockIdx.x;
  const int u0 = (MODE == 0) ? bid * UNITS : ((bid >> 1) * 56 + (bid & 1) * UNITS);
  const int T0 = u0 / 56;
  const int kb0 = T0 * 56, kb1 = kb0 + 56;
  const int tm0 = (T0 / NT) * 256, tn0 = (T0 % NT) * 256;
  const int tm1 = ((T0 + 1) / NT) * 256, tn1 = ((T0 + 1) % NT) * 256;
  const int tid = (int)threadIdx.x;
  const int wave = tid >> 6, lane = tid & 63;
  const int l15 = lane & 15, g = lane >> 4;
  const int wm = wave >> 2, wn = wave & 3;

  f32x4 acc[2][4][2][2] = {};  // [rh][mq][ch][nq]
  bf16x8 af[4][2], b0[2][2], b1[2][2];

#define STG_A(b, uu, h)                                                         \
  { const int kt_ = ((uu) >= kb1) ? ((uu) - kb1) : ((uu) - kb0);                \
    const int tmS_ = ((uu) >= kb1) ? tm1 : tm0;                                 \
    _Pragma("unroll") for (int j = 0; j < 2; ++j) {                             \
      const int lr = (h) * 128 + j * 64 + (tid >> 3);                           \
      const int wmm = (lr >> 6) & 1;                                            \
      const int rr = lr & 63;                                                   \
      const int grow = wmm * 128 + (h) * 64 + rr;                               \
      const int sc = (tid & 7) ^ (rr & 7);                                      \
      gll16(A + (size_t)(tmS_ + grow) * K + (size_t)kt_ * 64 + sc * 8,          \
            &As[b][((h) * 128 + j * 64 + wave * 8) * 64]);                      \
    } }
#define STG_B(b, uu, h)                                                         \
  { const int kt_ = ((uu) >= kb1) ? ((uu) - kb1) : ((uu) - kb0);                \
    const int tnS_ = ((uu) >= kb1) ? tn1 : tn0;                                 \
    _Pragma("unroll") for (int j = 0; j < 2; ++j) {                             \
      const int lr = (h) * 128 + j * 64 + (tid >> 3);                           \
      const int wnn = (lr >> 5) & 3;                                            \
      const int rr = lr & 31;                                                   \
      const int gcol = wnn * 64 + (h) * 32 + rr;                                \
      const int sc = (tid & 7) ^ (rr & 7);                                      \
      gll16(B + (size_t)(tnS_ + gcol) * K + (size_t)kt_ * 64 + sc * 8,          \
            &Bs[b][((h) * 128 + j * 64 + wave * 8) * 64]);                      \
    } }
#define LDA(buf, rh)                                                            \
  { _Pragma("unroll") for (int mq = 0; mq < 4; ++mq)                            \
      _Pragma("unroll") for (int ks = 0; ks < 2; ++ks) {                        \
        const int lr = (rh) * 128 + wm * 64 + mq * 16 + l15;                    \
        af[mq][ks] =                                                            \
            *(const bf16x8*)(&As[buf][lr * 64 + (((ks * 4 + g) ^ (lr & 7)) * 8)]); \
      } }
#define LDB(buf, ch, ARR)                                                       \
  { _Pragma("unroll") for (int nq = 0; nq < 2; ++nq)                            \
      _Pragma("unroll") for (int ks = 0; ks < 2; ++ks) {                        \
        const int lr = (ch) * 128 + wn * 32 + nq * 16 + l15;                    \
        ARR[nq][ks] =                                                           \
            *(const bf16x8*)(&Bs[buf][lr * 64 + (((ks * 4 + g) ^ (lr & 7)) * 8)]); \
      } }
#define VMW() { asm volatile("s_waitcnt vmcnt(4)" ::: "memory"); }
#define PH(RH, CH, BARR, TAILBLK)                                               \
  {                                                                             \
    __builtin_amdgcn_s_barrier();                                               \
    asm volatile("s_waitcnt lgkmcnt(0)" ::: "memory");                          \
    __builtin_amdgcn_sched_barrier(0);                                          \
    __builtin_amdgcn_s_setprio(1);                                              \
    _Pragma("unroll") for (int mq = 0; mq < 4; ++mq)                            \
      _Pragma("unroll") for (int nq = 0; nq < 2; ++nq) {                        \
        acc[RH][mq][CH][nq] = MFMA16(af[mq][0], BARR[nq][0], acc[RH][mq][CH][nq]); \
        acc[RH][mq][CH][nq] = MFMA16(af[mq][1], BARR[nq][1], acc[RH][mq][CH][nq]); \
      }                                                                         \
    __builtin_amdgcn_s_setprio(0);                                              \
    TAILBLK;                                                                    \
    __builtin_amdgcn_sched_barrier(0);                                          \
  }
#define EPI(tmS, tnS)                                                           \
  { _Pragma("unroll") for (int rh = 0; rh < 2; ++rh)                            \
    _Pragma("unroll") for (int mq = 0; mq < 4; ++mq)                            \
    _Pragma("unroll") for (int ch = 0; ch < 2; ++ch)                            \
    _Pragma("unroll") for (int nq = 0; nq < 2; ++nq) {                          \
      const int col = (tnS) + wn * 64 + ch * 32 + nq * 16 + l15;                \
      const int row0 = (tmS) + wm * 128 + rh * 64 + mq * 16 + g * 4;            \
      _Pragma("unroll") for (int r = 0; r < 4; ++r)                             \
        atomadd_f32(&Co[(size_t)(row0 + r) * N + col], acc[rh][mq][ch][nq][r]); \
    } }
#define RSTACC()                                                                \
  { _Pragma("unroll") for (int rh = 0; rh < 2; ++rh)                            \
    _Pragma("unroll") for (int mq = 0; mq < 4; ++mq)                            \
    _Pragma("unroll") for (int ch = 0; ch < 2; ++ch)                            \
    _Pragma("unroll") for (int nq = 0; nq < 2; ++nq)                            \
      acc[rh][mq][ch][nq] = f32x4{0.f, 0.f, 0.f, 0.f}; }

  // prologue: stage units u0 (buf0), u0+1 (buf1); drain u0; read P1 frags.
  STG_A(0, u0, 0); STG_A(0, u0, 1); STG_B(0, u0, 0); STG_B(0, u0, 1);
  STG_A(1, u0 + 1, 0); STG_A(1, u0 + 1, 1); STG_B(1, u0 + 1, 0); STG_B(1, u0 + 1, 1);
  asm volatile("s_waitcnt vmcnt(8)" ::: "memory");
  __builtin_amdgcn_s_barrier();
  LDA(0, 0); LDB(0, 0, b0);

#pragma unroll 1
  for (int i = 0; i < UNITS / 2; ++i) {
    const int uu2 = u0 + 2 * i + 2, uu3 = uu2 + 1;
    const bool more = (i < UNITS / 2 - 1);
    PH(0, 0, b0, { LDB(0, 1, b1); });
    PH(0, 1, b1, { if (more) STG_A(0, uu2, 0); LDA(0, 1); });
    PH(1, 1, b1, { if (more) { STG_B(0, uu2, 1); VMW(); }
                   else { asm volatile("s_waitcnt vmcnt(0)" ::: "memory"); } });
    PH(1, 0, b0, { if (more) { STG_A(0, uu2, 1); STG_B(0, uu2, 0); }
                   LDA(1, 0); LDB(1, 0, b0); });
    if (MODE == 0 && (u0 + 2 * i + 1 == kb1)) { EPI(tm0, tn0); RSTACC(); }
    PH(0, 0, b0, { LDB(1, 1, b1); });
    PH(0, 1, b1, { if (more) STG_A(1, uu3, 0); LDA(1, 1); });
    PH(1, 1, b1, { if (more) { STG_B(1, uu3, 1); VMW(); } });
    PH(1, 0, b0, { if (more) { STG_A(1, uu3, 1); STG_B(1, uu3, 0);
                               LDA(0, 0); LDB(0, 0, b0); } });
    if (MODE == 0 && more && (u0 + 2 * i + 2 == kb1)) { EPI(tm0, tn0); RSTACC(); }
  }
  {
    const bool ts = (u0 + UNITS - 1 >= kb1);
    const int tmL = ts ? tm1 : tm0, tnL = ts ? tn1 : tn0;
    EPI(tmL, tnL);
  }
#undef STG_A
#undef STG_B
#undef LDA
#undef LDB
#undef VMW
#undef PH
#undef EPI
#undef RSTACC
}

// ---------------- flash attention, 2-phase pipelined, paired q-tiles --------
__global__ void __launch_bounds__(256) attn_kernel(const short* __restrict__ qkv,
                                                   const short* __restrict__ vtb,
                                                   short* __restrict__ outb) {
  const int lid = (int)blockIdx.x + ((int)blockIdx.y << 4);
  const int kvh = (lid & 7) >> 1;
  const int u = ((lid >> 3) << 1) + (lid & 1);  // 0..111 within kv group
  const int head = kvh * 7 + (u >> 4);
  const int qtA = u & 15, qtB = 31 - qtA;

  const int tid = threadIdx.x;
  const int lane = tid & 63, wave = tid >> 6;
  const int l15 = lane & 15, g = lane >> 4;

  __shared__ short Ks[2][64 * 128];
  __shared__ short Vs[2][128 * 64];
  __shared__ short Ps[4][16 * 64];

  const short* kbase = qkv + 3584 + kvh * 128;
  const short* vbase = vtb + (size_t)kvh * 128 * 2048;
  const float NINF = -__builtin_inff();

  bf16x8 qf[4];
  f32x4 o[8];
  float mrun[4], lrun[4];

#define LOADQ(qt)                                                                  \
  {                                                                                \
    const short* qptr =                                                            \
        qkv + (size_t)((qt)*64 + wave * 16 + l15) * 4608 + head * 128 + g * 8;     \
    _Pragma("unroll") for (int ds = 0; ds < 4; ++ds) qf[ds] =                      \
        *(const bf16x8*)(qptr + ds * 32);                                          \
  }
#define RESET()                                                                    \
  {                                                                                \
    _Pragma("unroll") for (int nd = 0; nd < 8; ++nd) o[nd] = f32x4{0.f,0.f,0.f,0.f}; \
    _Pragma("unroll") for (int r = 0; r < 4; ++r) { mrun[r] = NINF; lrun[r] = 0.f; } \
  }
#define STAGE(kv, b)                                                               \
  {                                                                                \
    _Pragma("unroll") for (int it = 0; it < 4; ++it) {                             \
      const int chunk = it * 256 + tid;                                            \
      const int row = chunk >> 4, sc = (chunk & 15) ^ (row & 7);                   \
      gll16(kbase + (size_t)((kv)*64 + row) * 4608 + sc * 8,                       \
            &Ks[b][(it * 256 + wave * 64) * 8]);                                   \
    }                                                                              \
    _Pragma("unroll") for (int it = 0; it < 4; ++it) {                             \
      const int chunk = it * 256 + tid;                                            \
      const int row = chunk >> 3, sc = (chunk & 7) ^ (row & 7);                    \
      gll16(vbase + (size_t)row * 2048 + (kv)*64 + sc * 8,                         \
            &Vs[b][(it * 256 + wave * 64) * 8]);                                   \
    }                                                                              \
  }

  RESET();
  LOADQ(qtA);
  STAGE(0, 0);
  __syncthreads();
  int cur = 0;

  for (int s = 0; s < 33; ++s) {
    if (s < 32) {
      const int sn = s + 1;
      const int kvn = (sn <= qtA) ? sn : sn - qtA - 1;
      STAGE(kvn, cur ^ 1);
    }
    const int qt = (s <= qtA) ? qtA : qtB;
    const int kv = (s <= qtA) ? s : s - qtA - 1;
    const bool diag = (s == qtA) || (s == 32);

    f32x4 sf[4] = {};
    __builtin_amdgcn_s_setprio(1);
#pragma unroll
    for (int n = 0; n < 4; ++n) {
      const int krow = n * 16 + l15;
#pragma unroll
      for (int ds = 0; ds < 4; ++ds) {
        const int c = (ds * 4 + g) ^ (krow & 7);
        const bf16x8 kf = *(const bf16x8*)(&Ks[cur][krow * 128 + c * 8]);
        sf[n] = MFMA16(qf[ds], kf, sf[n]);
      }
    }
    __builtin_amdgcn_s_setprio(0);

    if (diag) {
#pragma unroll
      for (int r = 0; r < 4; ++r) {
        const int qr = qt * 64 + wave * 16 + g * 4 + r;
#pragma unroll
        for (int n = 0; n < 4; ++n)
          if (kv * 64 + n * 16 + l15 > qr) sf[n][r] = NINF;
      }
    }
    float pmax[4];
#pragma unroll
    for (int r = 0; r < 4; ++r)
      pmax[r] = fmaxf(fmaxf(sf[0][r], sf[1][r]), fmaxf(sf[2][r], sf[3][r]));
    const bool need = (pmax[0] > mrun[0] + 8.f) || (pmax[1] > mrun[1] + 8.f) ||
                      (pmax[2] > mrun[2] + 8.f) || (pmax[3] > mrun[3] + 8.f);
    if (__any(need)) {
#pragma unroll
      for (int r = 0; r < 4; ++r) {
        float mx = pmax[r];
        mx = fmaxf(mx, __shfl_xor(mx, 1));
        mx = fmaxf(mx, __shfl_xor(mx, 2));
        mx = fmaxf(mx, __shfl_xor(mx, 4));
        mx = fmaxf(mx, __shfl_xor(mx, 8));
        const float mnew = fmaxf(mrun[r], mx);
        const float alpha = exp2f(mrun[r] - mnew);
        mrun[r] = mnew;
        lrun[r] *= alpha;
#pragma unroll
        for (int nd = 0; nd < 8; ++nd) o[nd][r] *= alpha;
      }
    }
#pragma unroll
    for (int n = 0; n < 4; ++n) {
#pragma unroll
      for (int r = 0; r < 4; ++r) {
        const float p = exp2f(sf[n][r] - mrun[r]);
        lrun[r] += p;
        const int prow = g * 4 + r, key = n * 16 + l15;
        const int cp = (key >> 3) ^ (prow & 7);
        Ps[wave][prow * 64 + cp * 8 + (key & 7)] = f2bf(p);
      }
    }
    bf16x8 pf[2];
#pragma unroll
    for (int ksl = 0; ksl < 2; ++ksl) {
      const int c = (ksl * 4 + g) ^ (l15 & 7);
      pf[ksl] = *(const bf16x8*)(&Ps[wave][l15 * 64 + c * 8]);
    }
    __builtin_amdgcn_s_setprio(1);
#pragma unroll
    for (int nd = 0; nd < 8; ++nd) {
      const int vrow = nd * 16 + l15;
#pragma unroll
      for (int ksl = 0; ksl < 2; ++ksl) {
        const int c = (ksl * 4 + g) ^ (vrow & 7);
        const bf16x8 vf = *(const bf16x8*)(&Vs[cur][vrow * 64 + c * 8]);
        o[nd] = MFMA16(pf[ksl], vf, o[nd]);
      }
    }
    __builtin_amdgcn_s_setprio(0);

    if (diag) {
      float inv[4];
#pragma unroll
      for (int r = 0; r < 4; ++r) {
        float sum = lrun[r];
        sum += __shfl_xor(sum, 1);
        sum += __shfl_xor(sum, 2);
        sum += __shfl_xor(sum, 4);
        sum += __shfl_xor(sum, 8);
        inv[r] = 1.0f / sum;
      }
#pragma unroll
      for (int nd = 0; nd < 8; ++nd) {
#pragma unroll
        for (int r = 0; r < 4; ++r) {
          const int qr = qt * 64 + wave * 16 + g * 4 + r;
          outb[(size_t)qr * 3584 + head * 128 + nd * 16 + l15] = f2bf(o[nd][r] * inv[r]);
        }
      }
      if (s == qtA) {
        RESET();
        LOADQ(qtB);
      }
    }
    __syncthreads();
    cur ^= 1;
  }
#undef LOADQ
#undef RESET
#undef STAGE
}

extern "C" void kernel_launch(void* const* d_in, const int* in_sizes, int n_in,
                              void* d_out, int out_size, void* d_ws, size_t ws_size,
                              hipStream_t stream) {
  const float* h  = (const float*)d_in[0];
  const int* pos  = (const int*)d_in[1];
  const float* Wq = (const float*)d_in[2];
  const float* bq = (const float*)d_in[3];
  const float* Wk = (const float*)d_in[4];
  const float* bk = (const float*)d_in[5];
  const float* Wv = (const float*)d_in[6];
  const float* bv = (const float*)d_in[7];
  const float* Wo = (const float*)d_in[8];
  float* out = (float*)d_out;

  char* w = (char*)d_ws;
  short* hbf   = (short*)w; w += (size_t)2048 * 3584 * 2;
  short* Wall  = (short*)w; w += (size_t)4608 * 3584 * 2;
  short* qkvp  = (short*)w; w += (size_t)2048 * 4608 * 2;
  float* ctab  = (float*)w; w += 2048 * 64 * 4;
  float* stab  = (float*)w; w += 2048 * 64 * 4;
  short* vtb   = (short*)w; w += (size_t)4 * 128 * 2048 * 2;
  float* qkv32 = (float*)w; w += (size_t)2048 * 4608 * 4;
  short* attnb = hbf;   // hbf dead after QKV GEMM
  short* Wob = Wall;    // Wall dead after QKV GEMM

  hipMemsetAsync(qkv32, 0, (size_t)2048 * 4608 * 4, stream);
  hipMemsetAsync(out, 0, (size_t)2048 * 3584 * 4, stream);

  cvt_kernel<<<2048, 256, 0, stream>>>(h, hbf, (long long)2048 * 3584);
  cvt_kernel<<<2048, 256, 0, stream>>>(Wq, Wall, (long long)3584 * 3584);
  cvt_kernel<<<512, 256, 0, stream>>>(Wk, Wall + (size_t)3584 * 3584, (long long)512 * 3584);
  cvt_kernel<<<512, 256, 0, stream>>>(Wv, Wall + (size_t)4096 * 3584, (long long)512 * 3584);
  rope_table<<<2048, 64, 0, stream>>>(pos, ctab, stab);

  // QKV: 144 tiles x 56 ktiles = 8064 units = 252 blocks x 32
  gemm_sk<18, 32, 0><<<252, 512, 0, stream>>>(hbf, Wall, qkv32, 4608, 3584);

  cvt_kernel<<<2048, 256, 0, stream>>>(Wo, Wob, (long long)3584 * 3584);
  rope_apply2<<<2048, 256, 0, stream>>>(qkv32, bq, bk, ctab, stab, qkvp);
  v_transpose2<<<dim3(4, 32, 4), 256, 0, stream>>>(qkv32, bv, vtb);

  attn_kernel<<<dim3(16, 28), 256, 0, stream>>>(qkvp, vtb, attnb);

  // O-proj: 112 tiles, aligned split-2 = 224 blocks x 28 units
  gemm_sk<14, 28, 1><<<224, 512, 0, stream>>>(attnb, Wob, out, 3584, 3584);
}